// Round 2
// baseline (1013.598 us; speedup 1.0000x reference)
//
#include <hip/hip_runtime.h>
#include <stdint.h>

#define TOKENS 8192
#define IN_F   3072
#define OUT_F  8192
#define GROUP  128

// GEMM tiling: block 128(M) x 256(N), K-slab 64, 4 waves of 64x128 tiles
#define BM 128
#define BN 256
#define BK 64

typedef __bf16 bf16x8 __attribute__((ext_vector_type(8)));
typedef float  f32x4  __attribute__((ext_vector_type(4)));

// RNE float -> bf16 bits
__device__ __forceinline__ uint32_t f2bf(float f) {
    union { float f; uint32_t u; } v; v.f = f;
    uint32_t u = v.u;
    return (u + 0x7fffu + ((u >> 16) & 1u)) >> 16;
}

// async global -> LDS, 16 bytes per lane (global_load_lds_dwordx4)
__device__ __forceinline__ void async_cp16(const uint16_t* g, uint16_t* l) {
    __builtin_amdgcn_global_load_lds(
        (const __attribute__((address_space(1))) void*)g,
        (__attribute__((address_space(3))) void*)l,
        16, 0, 0);
}

// ---------------------------------------------------------------------------
// Kernel 1: dequantize packed int4 -> bf16 W [OUT_F, IN_F], scale per group.
// ---------------------------------------------------------------------------
__global__ __launch_bounds__(256) void dequant_w(const int* __restrict__ packed,
                                                 const float* __restrict__ scales,
                                                 uint16_t* __restrict__ W) {
    const int t   = blockIdx.x * 256 + threadIdx.x;
    const int idx = t * 4;                 // packed-element index
    const int row  = idx / (IN_F / 2);     // 1536 packed per row
    const int pcol = idx - row * (IN_F / 2);
    const int grp  = pcol >> 6;            // 64 packed = 128 cols per group
    const float s  = scales[row * (IN_F / GROUP) + grp];

    const int4 p = *(const int4*)(packed + idx);
    int vals[4] = {p.x, p.y, p.z, p.w};
    uint32_t w[4];
#pragma unroll
    for (int i = 0; i < 4; ++i) {
        int b  = vals[i] & 255;
        int lo = b & 15;        lo = (lo >= 8) ? lo - 16 : lo;
        int hi = (b >> 4) & 15; hi = (hi >= 8) ? hi - 16 : hi;
        uint32_t e = f2bf((float)lo * s);   // even column
        uint32_t o = f2bf((float)hi * s);   // odd column
        w[i] = e | (o << 16);
    }
    uint4 res = {w[0], w[1], w[2], w[3]};
    *(uint4*)(W + (size_t)idx * 2) = res;
}

// ---------------------------------------------------------------------------
// Kernel 2: x fp32 -> bf16. Each thread converts 8 floats (16B store).
// ---------------------------------------------------------------------------
__global__ __launch_bounds__(256) void cvt_x(const float* __restrict__ x,
                                             uint16_t* __restrict__ xb) {
    const size_t idx = ((size_t)blockIdx.x * 256 + threadIdx.x) * 8;
    const float4 a = *(const float4*)(x + idx);
    const float4 b = *(const float4*)(x + idx + 4);
    uint32_t w0 = f2bf(a.x) | (f2bf(a.y) << 16);
    uint32_t w1 = f2bf(a.z) | (f2bf(a.w) << 16);
    uint32_t w2 = f2bf(b.x) | (f2bf(b.y) << 16);
    uint32_t w3 = f2bf(b.z) | (f2bf(b.w) << 16);
    uint4 res = {w0, w1, w2, w3};
    *(uint4*)(xb + idx) = res;
}

// ---------------------------------------------------------------------------
// Kernel 3: C[M,N] = A[M,K] * B[N,K]^T + bias  (bf16 in, fp32 out)
// Block 128x256, BK=64, 4 waves each 64x128 (4x8 tiles of 16x16x32 MFMA).
// LDS chunk placement XOR-swizzled: slot s of row r holds global chunk
// s ^ (r&7), so 16-row fragment reads spread over all 32 banks (2-way = free).
// ---------------------------------------------------------------------------
__global__ __launch_bounds__(256) void gemm_bt(const uint16_t* __restrict__ A,
                                               const uint16_t* __restrict__ B,
                                               const float* __restrict__ bias,
                                               float* __restrict__ C) {
    constexpr int K = IN_F;
    constexpr int N = OUT_F;

    __shared__ __align__(16) uint16_t sA[BM * BK];   // 16 KiB
    __shared__ __align__(16) uint16_t sB[BN * BK];   // 32 KiB

    const int t    = threadIdx.x;
    const int lane = t & 63;
    const int wave = t >> 6;
    const int bx   = blockIdx.x;     // N tile (32)
    const int by   = blockIdx.y;     // M tile (64)
    const int wm   = (wave >> 1) * 64;    // wave M offset
    const int wn   = (wave & 1) * 128;    // wave N offset

    // --- staging: thread t covers LDS chunk ch = t + 256*p ---
    // row = ch>>3 = (t>>3) + 32p, slot = t&7 (const), global chunk = slot ^ (row&7)
    // (32p doesn't change row&7, so the swizzled global chunk is constant per thread)
    const int srow = t >> 3;                       // 0..31
    const int gch  = (t & 7) ^ (srow & 7);         // swizzled global 16B-chunk
    const uint16_t* gA = A + (size_t)(by * BM + srow) * K + gch * 8;
    const uint16_t* gB = B + (size_t)(bx * BN + srow) * K + gch * 8;
    uint16_t* lA = sA + t * 8;
    uint16_t* lB = sB + t * 8;

    const int fr = lane & 15;        // row within 16-tile
    const int qq = lane >> 4;        // k-chunk sub-index 0..3

    f32x4 acc[4][8] = {};

    for (int k0 = 0; k0 < K; k0 += BK) {
#pragma unroll
        for (int p = 0; p < 4; ++p)          // A: 128 rows x 64 = 1024 chunks
            async_cp16(gA + k0 + (size_t)(32 * p) * K, lA + 2048 * p);
#pragma unroll
        for (int p = 0; p < 8; ++p)          // B: 256 rows x 64 = 2048 chunks
            async_cp16(gB + k0 + (size_t)(32 * p) * K, lB + 2048 * p);
        __syncthreads();

#pragma unroll
        for (int ks = 0; ks < 2; ++ks) {     // two K=32 steps per BK=64 slab
            const int q = ks * 4 + qq;       // global chunk index 0..7
            bf16x8 af[4];
#pragma unroll
            for (int i = 0; i < 4; ++i) {
                const int row = wm + i * 16 + fr;
                af[i] = *(const bf16x8*)(sA + row * 64 + (q ^ (row & 7)) * 8);
            }
#pragma unroll
            for (int j = 0; j < 8; ++j) {
                const int row = wn + j * 16 + fr;
                const bf16x8 bf = *(const bf16x8*)(sB + row * 64 + (q ^ (row & 7)) * 8);
#pragma unroll
                for (int i = 0; i < 4; ++i)
                    acc[i][j] = __builtin_amdgcn_mfma_f32_16x16x32_bf16(af[i], bf, acc[i][j], 0, 0, 0);
            }
        }
        __syncthreads();
    }

    // --- epilogue: C/D layout col=lane&15, row=(lane>>4)*4+reg ---
    const int cr = (lane >> 4) * 4;
    const int cc = lane & 15;
#pragma unroll
    for (int j = 0; j < 8; ++j) {
        const int col = bx * BN + wn + j * 16 + cc;
        const float bv = bias[col];
#pragma unroll
        for (int i = 0; i < 4; ++i) {
            const size_t base = (size_t)(by * BM + wm + i * 16 + cr) * N + col;
#pragma unroll
            for (int r = 0; r < 4; ++r)
                C[base + (size_t)r * N] = acc[i][j][r] + bv;
        }
    }
}

extern "C" void kernel_launch(void* const* d_in, const int* in_sizes, int n_in,
                              void* d_out, int out_size, void* d_ws, size_t ws_size,
                              hipStream_t stream) {
    const float* x      = (const float*)d_in[0];   // [8192, 3072] fp32
    const int*   packed = (const int*)d_in[1];     // [8192, 1536] int32 (byte vals)
    const float* scales = (const float*)d_in[2];   // [8192, 24] fp32
    const float* bias   = (const float*)d_in[3];   // [8192] fp32
    float*       out    = (float*)d_out;           // [8192, 8192] fp32

    uint16_t* W  = (uint16_t*)d_ws;                                     // 50.3 MB bf16
    uint16_t* Xb = (uint16_t*)((char*)d_ws + (size_t)OUT_F * IN_F * 2); // 50.3 MB bf16

    const int dq_blocks  = (OUT_F * (IN_F / 2) / 4) / 256;   // 12288
    const int cvt_blocks = (TOKENS * IN_F / 8) / 256;        // 12288

    dequant_w<<<dq_blocks, 256, 0, stream>>>(packed, scales, W);
    cvt_x<<<cvt_blocks, 256, 0, stream>>>(x, Xb);

    dim3 grid(OUT_F / BN, TOKENS / BM);   // 32 x 64
    gemm_bt<<<grid, 256, 0, stream>>>(Xb, W, bias, out);
}

// Round 3
// 703.455 us; speedup vs baseline: 1.4409x; 1.4409x over previous
//
#include <hip/hip_runtime.h>
#include <stdint.h>

#define TOKENS 8192
#define IN_F   3072
#define OUT_F  8192
#define GROUP  128

// GEMM tiling: block 128x128, BK=64, 4 waves each 64x64 (acc[4][4] = 64 AGPR
// -> ~124 total regs/wave -> 3 blocks/CU; R2's 64x128 wave tile needed 280
// regs -> 1 block/CU -> occupancy crash).
#define BM 128
#define BN 128
#define BK 64

typedef __bf16 bf16x8 __attribute__((ext_vector_type(8)));
typedef float  f32x4  __attribute__((ext_vector_type(4)));

// RNE float -> bf16 bits
__device__ __forceinline__ uint32_t f2bf(float f) {
    union { float f; uint32_t u; } v; v.f = f;
    uint32_t u = v.u;
    return (u + 0x7fffu + ((u >> 16) & 1u)) >> 16;
}

// async global -> LDS, 16 bytes per lane (global_load_lds_dwordx4)
__device__ __forceinline__ void async_cp16(const uint16_t* g, uint16_t* l) {
    __builtin_amdgcn_global_load_lds(
        (const __attribute__((address_space(1))) void*)g,
        (__attribute__((address_space(3))) void*)l,
        16, 0, 0);
}

// ---------------------------------------------------------------------------
// Prep (one launch): blocks [0,12288) dequant packed int4 -> bf16 W;
// blocks [12288,24576) convert x fp32 -> bf16.
// ---------------------------------------------------------------------------
__global__ __launch_bounds__(256) void prep(const int* __restrict__ packed,
                                            const float* __restrict__ scales,
                                            const float* __restrict__ x,
                                            uint16_t* __restrict__ W,
                                            uint16_t* __restrict__ xb) {
    if (blockIdx.x < 12288) {
        // --- dequant W: each thread 4 packed int32 -> 8 bf16 (16B store) ---
        const int t   = blockIdx.x * 256 + threadIdx.x;
        const int idx = t * 4;                 // packed-element index
        const int row  = idx / (IN_F / 2);     // 1536 packed per row
        const int pcol = idx - row * (IN_F / 2);
        const int grp  = pcol >> 6;            // 64 packed = 128 cols per group
        const float s  = scales[row * (IN_F / GROUP) + grp];

        const int4 p = *(const int4*)(packed + idx);
        int vals[4] = {p.x, p.y, p.z, p.w};
        uint32_t w[4];
#pragma unroll
        for (int i = 0; i < 4; ++i) {
            int b  = vals[i] & 255;
            int lo = b & 15;        lo = (lo >= 8) ? lo - 16 : lo;
            int hi = (b >> 4) & 15; hi = (hi >= 8) ? hi - 16 : hi;
            uint32_t e = f2bf((float)lo * s);   // even column
            uint32_t o = f2bf((float)hi * s);   // odd column
            w[i] = e | (o << 16);
        }
        uint4 res = {w[0], w[1], w[2], w[3]};
        *(uint4*)(W + (size_t)idx * 2) = res;
    } else {
        // --- cvt x: each thread 8 floats -> 8 bf16 (16B store) ---
        const size_t idx = ((size_t)(blockIdx.x - 12288) * 256 + threadIdx.x) * 8;
        const float4 a = *(const float4*)(x + idx);
        const float4 b = *(const float4*)(x + idx + 4);
        uint32_t w0 = f2bf(a.x) | (f2bf(a.y) << 16);
        uint32_t w1 = f2bf(a.z) | (f2bf(a.w) << 16);
        uint32_t w2 = f2bf(b.x) | (f2bf(b.y) << 16);
        uint32_t w3 = f2bf(b.z) | (f2bf(b.w) << 16);
        uint4 res = {w0, w1, w2, w3};
        *(uint4*)(xb + idx) = res;
    }
}

// ---------------------------------------------------------------------------
// GEMM: C[M,N] = A[M,K] * B[N,K]^T + bias  (bf16 in, fp32 out)
// Block 128x128, BK=64, 4 waves each 64x64 (4x4 tiles of 16x16x32 MFMA).
// LDS 16B-chunk placement XOR-swizzled: slot s of row r holds global chunk
// s ^ (r&7) -> fragment reads are 2-way bank aliased = free (R2: 0 conflicts).
// ---------------------------------------------------------------------------
__global__ __launch_bounds__(256, 2) void gemm_bt(const uint16_t* __restrict__ A,
                                                  const uint16_t* __restrict__ B,
                                                  const float* __restrict__ bias,
                                                  float* __restrict__ C) {
    constexpr int K = IN_F;
    constexpr int N = OUT_F;

    __shared__ __align__(16) uint16_t sA[BM * BK];   // 16 KiB
    __shared__ __align__(16) uint16_t sB[BN * BK];   // 16 KiB

    const int t    = threadIdx.x;
    const int lane = t & 63;
    const int wave = t >> 6;
    const int bx   = blockIdx.x;          // N tile (64)
    const int by   = blockIdx.y;          // M tile (64)
    const int wm   = (wave >> 1) * 64;    // wave M offset
    const int wn   = (wave & 1) * 64;     // wave N offset

    // --- staging: thread t covers LDS chunk t + 256p (p=0..3) ---
    // row = (t>>3)+32p, slot = t&7; swizzled global chunk = slot ^ (row&7)
    // (row&7 invariant under +32p -> constant per thread)
    const int srow = t >> 3;                       // 0..31
    const int gch  = (t & 7) ^ (srow & 7);         // swizzled global 16B chunk
    const uint16_t* gA = A + (size_t)(by * BM + srow) * K + gch * 8;
    const uint16_t* gB = B + (size_t)(bx * BN + srow) * K + gch * 8;
    uint16_t* lA = sA + t * 8;
    uint16_t* lB = sB + t * 8;

    const int fr = lane & 15;        // row within 16-tile
    const int qq = lane >> 4;        // k-chunk sub-index 0..3

    f32x4 acc[4][4] = {};

    for (int k0 = 0; k0 < K; k0 += BK) {
#pragma unroll
        for (int p = 0; p < 4; ++p)   // A: 128 rows x 8 chunks = 1024
            async_cp16(gA + k0 + (size_t)(32 * p) * K, lA + 2048 * p);
#pragma unroll
        for (int p = 0; p < 4; ++p)   // B: 128 rows x 8 chunks = 1024
            async_cp16(gB + k0 + (size_t)(32 * p) * K, lB + 2048 * p);
        __syncthreads();

#pragma unroll
        for (int ks = 0; ks < 2; ++ks) {     // two K=32 steps per BK=64 slab
            const int q = ks * 4 + qq;       // logical chunk 0..7
            bf16x8 af[4], bf[4];
#pragma unroll
            for (int i = 0; i < 4; ++i) {
                const int row = wm + i * 16 + fr;
                af[i] = *(const bf16x8*)(sA + row * 64 + ((q ^ (row & 7)) * 8));
            }
#pragma unroll
            for (int j = 0; j < 4; ++j) {
                const int row = wn + j * 16 + fr;
                bf[j] = *(const bf16x8*)(sB + row * 64 + ((q ^ (row & 7)) * 8));
            }
#pragma unroll
            for (int i = 0; i < 4; ++i)
#pragma unroll
                for (int j = 0; j < 4; ++j)
                    acc[i][j] = __builtin_amdgcn_mfma_f32_16x16x32_bf16(af[i], bf[j], acc[i][j], 0, 0, 0);
        }
        __syncthreads();
    }

    // --- epilogue: C/D layout col=lane&15, row=(lane>>4)*4+reg ---
    const int cr = (lane >> 4) * 4;
    const int cc = lane & 15;
#pragma unroll
    for (int j = 0; j < 4; ++j) {
        const int col = bx * BN + wn + j * 16 + cc;
        const float bv = bias[col];
#pragma unroll
        for (int i = 0; i < 4; ++i) {
            const size_t base = (size_t)(by * BM + wm + i * 16 + cr) * N + col;
#pragma unroll
            for (int r = 0; r < 4; ++r)
                C[base + (size_t)r * N] = acc[i][j][r] + bv;
        }
    }
}

extern "C" void kernel_launch(void* const* d_in, const int* in_sizes, int n_in,
                              void* d_out, int out_size, void* d_ws, size_t ws_size,
                              hipStream_t stream) {
    const float* x      = (const float*)d_in[0];   // [8192, 3072] fp32
    const int*   packed = (const int*)d_in[1];     // [8192, 1536] int32 (byte vals)
    const float* scales = (const float*)d_in[2];   // [8192, 24] fp32
    const float* bias   = (const float*)d_in[3];   // [8192] fp32
    float*       out    = (float*)d_out;           // [8192, 8192] fp32

    uint16_t* W  = (uint16_t*)d_ws;                                     // 50.3 MB bf16
    uint16_t* Xb = (uint16_t*)((char*)d_ws + (size_t)OUT_F * IN_F * 2); // 50.3 MB bf16

    prep<<<24576, 256, 0, stream>>>(packed, scales, x, W, Xb);

    dim3 grid(OUT_F / BN, TOKENS / BM);   // 64 x 64
    gemm_bt<<<grid, 256, 0, stream>>>(Xb, W, bias, out);
}